// Round 11
// baseline (347.440 us; speedup 1.0000x reference)
//
#include <hip/hip_runtime.h>
#include <stdint.h>

// B=131072 rows, K=IN=256, N=OUT=256.
// temp = act @ weight.T (exact int32, |t| < 2^24); r = max|temp|;
// bw = ceil(log2(max(r,1))) (0 if r<=1); shift = bw-7;
// shift>0 ? round_shift(temp,shift) clipped to [-127,127] : int8-wrap(temp)
// exp_out = exp_in + weight_exp + max(shift,0)  (int16 semantics)
// Harness reads d_out as INT32: [B*N values, 1 exp scalar].
//
// R11: GEMM restructured per the canonical CDNA pattern. Weight (bf16,
// swizzled [k8][n 256][k32 32] by wconv) staged ONCE per block into 64 KB
// dynamic LDS via global_load_lds width=16; ONE barrier; then 16 waves run
// independently: per 16-row strip, A-fragments direct from global fp32
// (all 16 loads up-front = 1 latency exposure), pack to bf16, 8 k-steps of
// 8 conflict-free ds_read_b128 + 8 mfma, iv4 stores. No phase-locking.

#define M_ROWS 131072
#define NK 256

typedef __attribute__((ext_vector_type(8))) short bf16x8;
typedef __attribute__((ext_vector_type(4))) float f32x4;
typedef __attribute__((ext_vector_type(4))) float fv4;
typedef __attribute__((ext_vector_type(4))) int iv4;
typedef __attribute__((ext_vector_type(4))) unsigned short us4;

__device__ __forceinline__ uint32_t pack_bf16(float a, float b) {
  // exact for integer-valued floats |v| <= 255
  return (__float_as_uint(a) >> 16) | (__float_as_uint(b) & 0xFFFF0000u);
}

// Prepass: weight fp32 [n][k] -> bf16 swizzled [k8 = k>>5][n][k&31].
// 16384 fv4 reads; each thread: n = i>>6, k = (i&63)*4 (stays in one k8 chunk).
__global__ void wconv(const float* __restrict__ w, unsigned short* __restrict__ wb) {
  const int i = blockIdx.x * 256 + threadIdx.x;
  const int n = i >> 6;
  const int k = (i & 63) * 4;
  const fv4 f = ((const fv4*)w)[i];
  us4 o;
  o.x = (unsigned short)(__float_as_uint(f.x) >> 16);
  o.y = (unsigned short)(__float_as_uint(f.y) >> 16);
  o.z = (unsigned short)(__float_as_uint(f.z) >> 16);
  o.w = (unsigned short)(__float_as_uint(f.w) >> 16);
  *(us4*)&wb[(k >> 5) * 8192 + n * 32 + (k & 31)] = o;
}

// k1: 512 blocks x 1024 thr. Block b: N-half h=b&1 (cols h*128..+127),
// rows [ (b>>1)*512, +512 ). Wave w: two 16-row strips at +w*32, +w*32+16.
// LDS: 64 KB = weight half, [k8 8][n_local 128][k32 32] bf16 (8 KB chunks).
__global__ __launch_bounds__(1024, 4) void gemm_store_max(
    const float* __restrict__ act,           // [M,256] int-valued fp32
    const unsigned short* __restrict__ wgtb, // swizzled bf16 weight
    int* __restrict__ temp,                  // [M,256] int32 (d_ws)
    int* __restrict__ gmax)                  // [1] global abs-max (pre-zeroed)
{
  extern __shared__ __align__(16) char lds_raw[];   // 65536 B
  short* Bs = (short*)lds_raw;

  const int tid  = threadIdx.x;
  const int wave = tid >> 6;      // 0..15
  const int lane = tid & 63;
  const int l15  = lane & 15;
  const int lq   = lane >> 4;     // 0..3
  const int h    = blockIdx.x & 1;
  const int g    = blockIdx.x >> 1;

  // ---- stage weight half into LDS: 64 segs of 1 KB; wave w does segs w*4+j.
  // seg s: k8 = s>>3; global = wb + k8*16384B + h*8192B + (s&7)*1024B + lane*16
  //        lds    = s*1024B + lane*16   (wave-uniform base + lane*16: OK)
#pragma unroll
  for (int j = 0; j < 4; ++j) {
    const int seg = wave * 4 + j;
    const char* gsrc = (const char*)wgtb + (seg >> 3) * 16384 + h * 8192 +
                       (seg & 7) * 1024 + lane * 16;
    char* ldst = lds_raw + seg * 1024 + lane * 16;
    __builtin_amdgcn_global_load_lds(
        (const __attribute__((address_space(1))) unsigned int*)gsrc,
        (__attribute__((address_space(3))) unsigned int*)ldst, 16, 0, 0);
  }
  __syncthreads();   // the only barrier

  int imax = 0;

#pragma unroll
  for (int s = 0; s < 2; ++s) {
    const int m0 = g * 512 + wave * 32 + s * 16;
    const float* ap = act + (size_t)(m0 + l15) * NK + lq * 8;

    // all 16 A-loads up-front (one latency exposure), then pack
    fv4 a0[8], a1[8];
#pragma unroll
    for (int k8 = 0; k8 < 8; ++k8) {
      a0[k8] = *(const fv4*)(ap + k8 * 32);
      a1[k8] = *(const fv4*)(ap + k8 * 32 + 4);
    }
    bf16x8 af[8];
#pragma unroll
    for (int k8 = 0; k8 < 8; ++k8) {
      uint32_t pk[4];
      pk[0] = pack_bf16(a0[k8].x, a0[k8].y);
      pk[1] = pack_bf16(a0[k8].z, a0[k8].w);
      pk[2] = pack_bf16(a1[k8].x, a1[k8].y);
      pk[3] = pack_bf16(a1[k8].z, a1[k8].w);
      af[k8] = *(const bf16x8*)pk;
    }

    f32x4 acc[8] = {};
#pragma unroll
    for (int k8 = 0; k8 < 8; ++k8) {
      const int cbase = k8 * 4096 + l15 * 32 + lq * 8;   // short index
#pragma unroll
      for (int ni = 0; ni < 8; ++ni) {
        const bf16x8 bfr = *(const bf16x8*)&Bs[cbase + ni * 512];
        // mfma(B-data, A-data): D[m = lane&15 (=l15)][n = lq*4+r]
        acc[ni] = __builtin_amdgcn_mfma_f32_16x16x32_bf16(bfr, af[k8], acc[ni], 0, 0, 0);
      }
    }

    // store: row m0+l15, cols h*128 + ni*16 + lq*4 .. +3
    int* orow = temp + (size_t)(m0 + l15) * NK + h * 128 + lq * 4;
#pragma unroll
    for (int ni = 0; ni < 8; ++ni) {
      iv4 qv;
#pragma unroll
      for (int r = 0; r < 4; ++r) {
        const int iv = (int)acc[ni][r];
        qv[r] = iv;
        const int a = iv < 0 ? -iv : iv;
        imax = a > imax ? a : imax;
      }
      *(iv4*)&orow[ni * 16] = qv;
    }
  }

  // wave max-reduce, one global atomic per wave
#pragma unroll
  for (int off = 32; off; off >>= 1) {
    const int o = __shfl_xor(imax, off, 64);
    imax = o > imax ? o : imax;
  }
  if (lane == 0) atomicMax(gmax, imax);
}

// k2: streaming quantize temp (LLC-hot) -> out (nt). 8192 blocks x 256 thr,
// 4 iv4/thread interleaved: idx = block*1024 + j*256 + tid (coalesced).
__global__ __launch_bounds__(256) void quant_stream(
    const int* __restrict__ temp, int* __restrict__ out,
    const int* __restrict__ gmax,
    const int* __restrict__ exp_in, const int* __restrict__ wexp)
{
  const int r = *gmax;
  const int bw = (r <= 1) ? 0 : (32 - __clz(r - 1));   // ceil(log2(r))
  const int shift = bw - 7;
  const bool pos = shift > 0;
  const int s = shift < 1 ? 1 : shift;

  const int base = blockIdx.x * 1024 + threadIdx.x;
  const iv4* pin = (const iv4*)temp;
  iv4* pout = (iv4*)out;

  iv4 v[4];
#pragma unroll
  for (int j = 0; j < 4; ++j) v[j] = pin[base + j * 256];   // 4 loads in flight

#pragma unroll
  for (int j = 0; j < 4; ++j) {
    iv4 o;
#pragma unroll
    for (int e = 0; e < 4; ++e) {
      const int ti = v[j][e];
      int q;
      if (pos) {
        const int rt = ti >> s;                       // floor(t / 2^s)
        const int dec = (ti - (rt << s)) >> (s - 1);  // {0,1}
        q = rt + dec;
        q = q > 127 ? 127 : (q < -127 ? -127 : q);
      } else {
        q = (int)(signed char)(ti & 0xFF);            // int8 wrap
      }
      o[e] = q;
    }
    __builtin_nontemporal_store(o, &pout[base + j * 256]);
  }

  if (base == 0) {
    const int e = exp_in[0] + wexp[0] + (pos ? shift : 0);
    out[(size_t)M_ROWS * NK] = (int)(short)e;
  }
}

extern "C" void kernel_launch(void* const* d_in, const int* in_sizes, int n_in,
                              void* d_out, int out_size, void* d_ws, size_t ws_size,
                              hipStream_t stream) {
  const float* act   = (const float*)d_in[0];
  const int* exp_in  = (const int*)d_in[1];
  const float* wgt   = (const float*)d_in[2];
  const int* wexp    = (const int*)d_in[3];

  int* gmax          = (int*)d_ws;
  unsigned short* wb = (unsigned short*)((char*)d_ws + 4096);        // 128 KB
  int* temp          = (int*)((char*)d_ws + (1 << 20));              // 134 MB

  (void)hipMemsetAsync(d_ws, 0, sizeof(int), stream);
  wconv<<<dim3(64), dim3(256), 0, stream>>>(wgt, wb);
  gemm_store_max<<<dim3(512), dim3(1024), 65536, stream>>>(act, wb, temp, gmax);
  quant_stream<<<dim3(8192), dim3(256), 0, stream>>>(temp, (int*)d_out, gmax,
                                                     exp_in, wexp);
}